// Round 1
// baseline (657.277 us; speedup 1.0000x reference)
//
#include <hip/hip_runtime.h>
#include <hip/hip_bf16.h>
#include <stdint.h>

#define OUT_F 8192
#define IN_F  8192
#define RANK  16
#define M_TOT 1024   // B*S
#define BM 128
#define BN 128
#define BK 64
#define WP 72        // padded LDS row stride for weight tile (elements)

typedef __bf16 bf16x8 __attribute__((ext_vector_type(8)));
typedef float  f32x4  __attribute__((ext_vector_type(4)));

// round-half-up f32->bf16 pack of two floats into one uint32 (lo in low half)
static __device__ __forceinline__ uint32_t pack_bf16(float lo, float hi) {
    uint32_t a = __builtin_bit_cast(uint32_t, lo);
    uint32_t b = __builtin_bit_cast(uint32_t, hi);
    return ((a + 0x8000u) >> 16) | ((b + 0x8000u) & 0xffff0000u);
}

// ---------------------------------------------------------------------------
// Kernel 1: per token-row m — convert x row fp32->bf16 into ws, and compute
// t[m,r] = sum_i x[m,i] * lora_A[r,i]   (t used to fold LoRA into the GEMM)
// ---------------------------------------------------------------------------
__global__ __launch_bounds__(256) void prep_kernel(
    const float* __restrict__ x, const float* __restrict__ lora_A,
    uint2* __restrict__ xb2, float* __restrict__ t)
{
    const int m   = blockIdx.x;
    const int tid = threadIdx.x;
    const float4* x4 = (const float4*)(x + (size_t)m * IN_F);
    uint2* xout = xb2 + (size_t)m * (IN_F / 4);

    float acc[RANK];
#pragma unroll
    for (int r = 0; r < RANK; ++r) acc[r] = 0.f;

#pragma unroll
    for (int j = 0; j < 8; ++j) {
        const int idx4 = tid + 256 * j;      // float4 index within row
        const float4 v = x4[idx4];
        uint2 p;
        p.x = pack_bf16(v.x, v.y);
        p.y = pack_bf16(v.z, v.w);
        xout[idx4] = p;
        const int i = idx4 * 4;
#pragma unroll
        for (int r = 0; r < RANK; ++r) {
            const float4 a = *(const float4*)(lora_A + (size_t)r * IN_F + i);
            acc[r] += v.x * a.x + v.y * a.y + v.z * a.z + v.w * a.w;
        }
    }
    // reduce across 64-lane wave, then across 4 waves via LDS
#pragma unroll
    for (int r = 0; r < RANK; ++r) {
        float v = acc[r];
        for (int off = 32; off > 0; off >>= 1) v += __shfl_down(v, off, 64);
        acc[r] = v;
    }
    __shared__ float part[4][RANK];
    const int wave = tid >> 6, lane = tid & 63;
    if (lane == 0) {
#pragma unroll
        for (int r = 0; r < RANK; ++r) part[wave][r] = acc[r];
    }
    __syncthreads();
    if (tid < RANK)
        t[(size_t)m * RANK + tid] = part[0][tid] + part[1][tid] + part[2][tid] + part[3][tid];
}

// ---------------------------------------------------------------------------
// Kernel 2: fused dequant GEMM. 128x128 output tile / block, BK=64,
// 4 waves each computing a 64x64 subtile with 4x4 mfma_f32_16x16x32_bf16.
// LoRA folded in as one extra K=32 MFMA step (t vs 2*lora_B), bias in epilogue.
// ---------------------------------------------------------------------------
__global__ __launch_bounds__(256, 2) void gemm_kernel(
    const uint16_t* __restrict__ xb,    // bf16 x  [1024][8192] (in ws)
    const int*      __restrict__ q,     // int32   [8192][8192]
    const float*    __restrict__ scales,// fp32    [8192][256]
    const float*    __restrict__ t,     // fp32    [1024][16]   (in ws)
    const float*    __restrict__ loraB, // fp32    [8192][16]
    const float*    __restrict__ bias,  // fp32    [8192]
    float*          __restrict__ out)   // fp32    [1024][8192]
{
    __shared__ __align__(16) uint16_t xs[BM * BK];   // 16 KB, bf16 A tile (no pad: global_load_lds)
    __shared__ __align__(16) uint16_t wt[BN * WP];   // 18 KB, bf16 W tile (+8 pad)

    const int bx    = blockIdx.x;
    const int mtile = bx >> 6;          // 0..7   (same-ntile blocks share XCD: bx%8 == ntile%8)
    const int ntile = bx & 63;          // 0..63
    const int m0 = mtile * BM;
    const int n0 = ntile * BN;

    const int tid  = threadIdx.x;
    const int wave = tid >> 6;
    const int lane = tid & 63;
    const int wm = wave & 1, wn = wave >> 1;   // 64x64 wave subtile
    const int fr = lane & 15;                  // fragment row (A) / col (B)
    const int fk = (lane >> 4) * 8;            // fragment k offset
    const int quad = lane >> 4;

    // q staging map: flat int4 index idx = tid + 256*j over the 128x64 tile
    const int qrow_base = tid >> 4;            // + 16*j
    const int qcol4     = (tid & 15) * 4;      // k-local int offset
    const int qhi       = (tid >> 3) & 1;      // which 32-block of the 64-wide tile

    f32x4 acc[4][4];
    const f32x4 z = {0.f, 0.f, 0.f, 0.f};
#pragma unroll
    for (int i = 0; i < 4; ++i)
#pragma unroll
        for (int j = 0; j < 4; ++j) acc[i][j] = z;

    // ---- LoRA as one K=32 MFMA step: A'=t[m][r], B'=2*loraB[o][r], zero-padded
    {
        if (tid < 128) {
            const int row = tid;
            const float4* tp = (const float4*)(t + (size_t)(m0 + row) * RANK);
            const float4 v0 = tp[0], v1 = tp[1], v2 = tp[2], v3 = tp[3];
            uint32_t* dst = (uint32_t*)(xs + row * BK);
            dst[0] = pack_bf16(v0.x, v0.y); dst[1] = pack_bf16(v0.z, v0.w);
            dst[2] = pack_bf16(v1.x, v1.y); dst[3] = pack_bf16(v1.z, v1.w);
            dst[4] = pack_bf16(v2.x, v2.y); dst[5] = pack_bf16(v2.z, v2.w);
            dst[6] = pack_bf16(v3.x, v3.y); dst[7] = pack_bf16(v3.z, v3.w);
#pragma unroll
            for (int i = 8; i < 16; ++i) dst[i] = 0;
        } else {
            const int row = tid - 128;
            const float4* bp = (const float4*)(loraB + (size_t)(n0 + row) * RANK);
            const float4 v0 = bp[0], v1 = bp[1], v2 = bp[2], v3 = bp[3];
            uint32_t* dst = (uint32_t*)(wt + row * WP);
            dst[0] = pack_bf16(2.f * v0.x, 2.f * v0.y); dst[1] = pack_bf16(2.f * v0.z, 2.f * v0.w);
            dst[2] = pack_bf16(2.f * v1.x, 2.f * v1.y); dst[3] = pack_bf16(2.f * v1.z, 2.f * v1.w);
            dst[4] = pack_bf16(2.f * v2.x, 2.f * v2.y); dst[5] = pack_bf16(2.f * v2.z, 2.f * v2.w);
            dst[6] = pack_bf16(2.f * v3.x, 2.f * v3.y); dst[7] = pack_bf16(2.f * v3.z, 2.f * v3.w);
#pragma unroll
            for (int i = 8; i < 16; ++i) dst[i] = 0;
        }
        __syncthreads();
        bf16x8 af[4], bfr[4];
#pragma unroll
        for (int i = 0; i < 4; ++i)
            af[i] = *(const bf16x8*)(xs + (wm * 64 + i * 16 + fr) * BK + fk);
#pragma unroll
        for (int j = 0; j < 4; ++j)
            bfr[j] = *(const bf16x8*)(wt + (wn * 64 + j * 16 + fr) * WP + fk);
#pragma unroll
        for (int i = 0; i < 4; ++i)
#pragma unroll
            for (int j = 0; j < 4; ++j)
                acc[i][j] = __builtin_amdgcn_mfma_f32_16x16x32_bf16(af[i], bfr[j], acc[i][j], 0, 0, 0);
    }

    const int* qbase = q + (size_t)n0 * IN_F + qcol4;
    const uint16_t* xsrc = xb + (size_t)(m0 + wave * 32 + (lane >> 3)) * IN_F + (lane & 7) * 8;

    for (int kt = 0; kt < IN_F / BK; ++kt) {
        __syncthreads();   // previous iter's LDS reads complete

        // stage A tile via async global->LDS (16B/lane); wave covers 32 rows
        {
            const uint16_t* g = xsrc + kt * BK;
#pragma unroll
            for (int i = 0; i < 4; ++i) {
                __builtin_amdgcn_global_load_lds(
                    (const __attribute__((address_space(1))) uint32_t*)(g + (size_t)i * 8 * IN_F),
                    (__attribute__((address_space(3))) uint32_t*)(xs + (wave * 32 + i * 8) * BK),
                    16, 0, 0);
            }
        }
        // stage W tile: coalesced int4 q loads -> dequant -> bf16 ds_write
        {
            int4  qv[8];
            float sc[8];
#pragma unroll
            for (int j = 0; j < 8; ++j) {
                const int row = qrow_base + 16 * j;
                qv[j] = *(const int4*)(qbase + (size_t)row * IN_F + kt * 64);
                sc[j] = scales[(size_t)(n0 + row) * (IN_F / 32) + kt * 2 + qhi];
            }
#pragma unroll
            for (int j = 0; j < 8; ++j) {
                const float s = sc[j];
                const float c = -128.f * s;
                const float f0 = fmaf((float)qv[j].x, s, c);
                const float f1 = fmaf((float)qv[j].y, s, c);
                const float f2 = fmaf((float)qv[j].z, s, c);
                const float f3 = fmaf((float)qv[j].w, s, c);
                uint2 p;
                p.x = pack_bf16(f0, f1);
                p.y = pack_bf16(f2, f3);
                const int row = qrow_base + 16 * j;
                *(uint2*)(wt + row * WP + qcol4) = p;
            }
        }
        __syncthreads();   // drains vmcnt (global_load_lds) + lgkm (ds_write)

        // MFMA over the 64-wide K tile
#pragma unroll
        for (int kk = 0; kk < BK; kk += 32) {
            bf16x8 af[4], bfr[4];
#pragma unroll
            for (int i = 0; i < 4; ++i)
                af[i] = *(const bf16x8*)(xs + (wm * 64 + i * 16 + fr) * BK + kk + fk);
#pragma unroll
            for (int j = 0; j < 4; ++j)
                bfr[j] = *(const bf16x8*)(wt + (wn * 64 + j * 16 + fr) * WP + kk + fk);
#pragma unroll
            for (int i = 0; i < 4; ++i)
#pragma unroll
                for (int j = 0; j < 4; ++j)
                    acc[i][j] = __builtin_amdgcn_mfma_f32_16x16x32_bf16(af[i], bfr[j], acc[i][j], 0, 0, 0);
        }
    }

    // epilogue: + bias, store fp32 (C/D map: col=lane&15, row=quad*4+reg — m89/m91)
#pragma unroll
    for (int j = 0; j < 4; ++j) {
        const int col = n0 + wn * 64 + j * 16 + fr;
        const float bv = bias[col];
#pragma unroll
        for (int i = 0; i < 4; ++i) {
            const int rbase = m0 + wm * 64 + i * 16 + quad * 4;
#pragma unroll
            for (int r = 0; r < 4; ++r)
                out[(size_t)(rbase + r) * OUT_F + col] = acc[i][j][r] + bv;
        }
    }
}

extern "C" void kernel_launch(void* const* d_in, const int* in_sizes, int n_in,
                              void* d_out, int out_size, void* d_ws, size_t ws_size,
                              hipStream_t stream) {
    const float* x      = (const float*)d_in[0];
    const int*   q      = (const int*)d_in[1];
    const float* scales = (const float*)d_in[2];
    const float* lora_A = (const float*)d_in[3];
    const float* lora_B = (const float*)d_in[4];
    const float* bias   = (const float*)d_in[5];
    float* out = (float*)d_out;

    // ws layout: [0,16MB) xb bf16[1024][8192]; then t fp32[1024][16]
    uint16_t* xb = (uint16_t*)d_ws;
    float*    t  = (float*)((char*)d_ws + (size_t)M_TOT * IN_F * sizeof(uint16_t));

    prep_kernel<<<M_TOT, 256, 0, stream>>>(x, lora_A, (uint2*)xb, t);
    gemm_kernel<<<(M_TOT / BM) * (OUT_F / BN), 256, 0, stream>>>(
        xb, q, scales, t, lora_B, bias, out);
}

// Round 2
// 624.624 us; speedup vs baseline: 1.0523x; 1.0523x over previous
//
#include <hip/hip_runtime.h>
#include <hip/hip_bf16.h>
#include <stdint.h>

#define OUT_F 8192
#define IN_F  8192
#define RANK  16
#define M_TOT 1024   // B*S
#define BM 128
#define BN 64
#define BK 64
#define WP 72        // padded LDS row stride for weight tile (elements)
#define NK (IN_F / BK)   // 128

typedef __bf16 bf16x8 __attribute__((ext_vector_type(8)));
typedef float  f32x4  __attribute__((ext_vector_type(4)));

// round-half-up f32->bf16 pack of two floats into one uint32 (lo in low half)
static __device__ __forceinline__ uint32_t pack_bf16(float lo, float hi) {
    uint32_t a = __builtin_bit_cast(uint32_t, lo);
    uint32_t b = __builtin_bit_cast(uint32_t, hi);
    return ((a + 0x8000u) >> 16) | ((b + 0x8000u) & 0xffff0000u);
}

// ---------------------------------------------------------------------------
// Kernel 1: streaming fp32 -> bf16 convert of x into ws; blocks 0..63 also
// zero t (stream order guarantees t is zeroed before lora_t_kernel runs).
// ---------------------------------------------------------------------------
__global__ __launch_bounds__(256) void convert_kernel(
    const float* __restrict__ x, uint2* __restrict__ xb2, float* __restrict__ t)
{
    const int tid = threadIdx.x, b = blockIdx.x;
    if (b < 64) t[b * 256 + tid] = 0.f;
    const float4* x4 = (const float4*)x;
    const int base = b * 256 + tid;
#pragma unroll
    for (int j = 0; j < 8; ++j) {
        const int i = base + j * 262144;       // 2M float4 total
        const float4 v = x4[i];
        uint2 p;
        p.x = pack_bf16(v.x, v.y);
        p.y = pack_bf16(v.z, v.w);
        xb2[i] = p;
    }
}

// ---------------------------------------------------------------------------
// Kernel 2: t = x @ lora_A^T via MFMA split-K + atomicAdd.
// 256 blocks = 16 m-tiles(64 rows) x 16 k-splits(512). Block = 4 waves,
// each wave one 16-row MFMA tile, 16 K-steps of mfma_f32_16x16x32_bf16.
// ---------------------------------------------------------------------------
__global__ __launch_bounds__(256) void lora_t_kernel(
    const float* __restrict__ x, const float* __restrict__ lora_A,
    float* __restrict__ t)
{
    const int b = blockIdx.x;
    const int mt = b >> 4, ks = b & 15;
    const int tid = threadIdx.x, wave = tid >> 6, lane = tid & 63;
    const int fr = lane & 15, quad = lane >> 4;
    const int m = mt * 64 + wave * 16 + fr;
    const int k0 = ks * 512 + quad * 8;

    f32x4 acc = {0.f, 0.f, 0.f, 0.f};
    const float* xr = x + (size_t)m * IN_F + k0;
    const float* ar = lora_A + (size_t)fr * IN_F + k0;

#pragma unroll 4
    for (int s = 0; s < 16; ++s) {
        const float4 x0 = *(const float4*)(xr + s * 32);
        const float4 x1 = *(const float4*)(xr + s * 32 + 4);
        const float4 a0 = *(const float4*)(ar + s * 32);
        const float4 a1 = *(const float4*)(ar + s * 32 + 4);
        bf16x8 af, bfr;
        uint32_t* ap = (uint32_t*)&af;
        uint32_t* bp = (uint32_t*)&bfr;
        ap[0] = pack_bf16(x0.x, x0.y); ap[1] = pack_bf16(x0.z, x0.w);
        ap[2] = pack_bf16(x1.x, x1.y); ap[3] = pack_bf16(x1.z, x1.w);
        bp[0] = pack_bf16(a0.x, a0.y); bp[1] = pack_bf16(a0.z, a0.w);
        bp[2] = pack_bf16(a1.x, a1.y); bp[3] = pack_bf16(a1.z, a1.w);
        acc = __builtin_amdgcn_mfma_f32_16x16x32_bf16(af, bfr, acc, 0, 0, 0);
    }
    // C/D map: col=lane&15 (rank), row=quad*4+reg (m within the 16-row tile)
    const int mout = mt * 64 + wave * 16 + quad * 4;
#pragma unroll
    for (int r = 0; r < 4; ++r)
        atomicAdd(&t[(size_t)(mout + r) * RANK + fr], acc[r]);
}

// ---------------------------------------------------------------------------
// Kernel 3: fused dequant GEMM. 128x64 output tile / block (grid 1024 =
// 4 blocks/CU), BK=64, 4 waves each computing a 64x32 subtile with 4x2
// mfma_f32_16x16x32_bf16. xs uses an XOR chunk swizzle (realized through the
// global-side lane permutation of global_load_lds) to kill the 16-way bank
// conflict on af reads. q int4 loads are register-double-buffered, issued
// after barrier B so HBM latency overlaps the MFMA phase.
// ---------------------------------------------------------------------------
__global__ __launch_bounds__(256, 4) void gemm_kernel(
    const uint16_t* __restrict__ xb,    // bf16 x  [1024][8192] (in ws)
    const int*      __restrict__ q,     // int32   [8192][8192]
    const float*    __restrict__ scales,// fp32    [8192][256]
    const float*    __restrict__ t,     // fp32    [1024][16]   (in ws)
    const float*    __restrict__ loraB, // fp32    [8192][16]
    const float*    __restrict__ bias,  // fp32    [8192]
    float*          __restrict__ out)   // fp32    [1024][8192]
{
    __shared__ __align__(16) uint16_t xs[BM * BK];   // 16 KB, swizzled bf16 A tile
    __shared__ __align__(16) uint16_t wt[BN * WP];   //  9 KB, bf16 W tile (+8 pad)

    const int bx    = blockIdx.x;
    const int mtile = bx >> 7;          // 0..7
    const int ntile = bx & 127;         // 0..127 (same-ntile blocks: bx%8 equal -> same XCD)
    const int m0 = mtile * BM;
    const int n0 = ntile * BN;

    const int tid  = threadIdx.x;
    const int wave = tid >> 6;
    const int lane = tid & 63;
    const int wm = wave & 1, wn = wave >> 1;   // 64x32 wave subtile
    const int fr = lane & 15;
    const int quad = lane >> 4;
    const int fk = quad * 8;

    // q staging map: flat int4 index idx = tid + 256*j over the 64x64 tile
    const int qrow  = tid >> 4;            // + 16*j, j<4
    const int qcol4 = (tid & 15) * 4;
    const int qhi   = (tid >> 3) & 1;

    f32x4 acc[4][2];
    const f32x4 z = {0.f, 0.f, 0.f, 0.f};
#pragma unroll
    for (int i = 0; i < 4; ++i)
#pragma unroll
        for (int j = 0; j < 2; ++j) acc[i][j] = z;

    // ---- initial q prefetch for kt=0 (latency hidden by the LoRA prologue)
    const int* qbase = q + (size_t)n0 * IN_F + qcol4;
    int4  qv[4];
    float sc[4];
#pragma unroll
    for (int j = 0; j < 4; ++j) {
        const int row = qrow + 16 * j;
        qv[j] = *(const int4*)(qbase + (size_t)row * IN_F);
        sc[j] = scales[(size_t)(n0 + row) * (IN_F / 32) + qhi];
    }

    // ---- LoRA as one K=32 MFMA step: A'=t[m][r], B'=2*loraB[o][r], zero-padded
    {
        if (tid < 128) {
            const int row = tid;
            const int s = row & 7;
            const float4* tp = (const float4*)(t + (size_t)(m0 + row) * RANK);
            const float4 v0 = tp[0], v1 = tp[1], v2 = tp[2], v3 = tp[3];
            uint32_t vals[8];
            vals[0] = pack_bf16(v0.x, v0.y); vals[1] = pack_bf16(v0.z, v0.w);
            vals[2] = pack_bf16(v1.x, v1.y); vals[3] = pack_bf16(v1.z, v1.w);
            vals[4] = pack_bf16(v2.x, v2.y); vals[5] = pack_bf16(v2.z, v2.w);
            vals[6] = pack_bf16(v3.x, v3.y); vals[7] = pack_bf16(v3.z, v3.w);
            uint32_t* dst = (uint32_t*)(xs + row * BK);
#pragma unroll
            for (int c = 0; c < 8; ++c) {          // chunk c stored at position c^s
                const int p = (c ^ s) * 4;
                if (c < 2) {
                    dst[p + 0] = vals[c * 4 + 0]; dst[p + 1] = vals[c * 4 + 1];
                    dst[p + 2] = vals[c * 4 + 2]; dst[p + 3] = vals[c * 4 + 3];
                } else {
                    dst[p + 0] = 0; dst[p + 1] = 0; dst[p + 2] = 0; dst[p + 3] = 0;
                }
            }
        } else if (tid < 192) {
            const int row = tid - 128;             // 0..63
            const float4* bp = (const float4*)(loraB + (size_t)(n0 + row) * RANK);
            const float4 v0 = bp[0], v1 = bp[1], v2 = bp[2], v3 = bp[3];
            uint32_t* dst = (uint32_t*)(wt + row * WP);
            dst[0] = pack_bf16(2.f * v0.x, 2.f * v0.y); dst[1] = pack_bf16(2.f * v0.z, 2.f * v0.w);
            dst[2] = pack_bf16(2.f * v1.x, 2.f * v1.y); dst[3] = pack_bf16(2.f * v1.z, 2.f * v1.w);
            dst[4] = pack_bf16(2.f * v2.x, 2.f * v2.y); dst[5] = pack_bf16(2.f * v2.z, 2.f * v2.w);
            dst[6] = pack_bf16(2.f * v3.x, 2.f * v3.y); dst[7] = pack_bf16(2.f * v3.z, 2.f * v3.w);
#pragma unroll
            for (int i = 8; i < 16; ++i) dst[i] = 0;
        }
        __syncthreads();
        bf16x8 af[4], bfr[2];
#pragma unroll
        for (int i = 0; i < 4; ++i) {
            const int R = wm * 64 + i * 16 + fr;
            const int p = (quad ^ (fr & 7)) * 8;   // kk=0: chunk=quad
            af[i] = *(const bf16x8*)(xs + R * BK + p);
        }
#pragma unroll
        for (int j = 0; j < 2; ++j)
            bfr[j] = *(const bf16x8*)(wt + (wn * 32 + j * 16 + fr) * WP + fk);
#pragma unroll
        for (int i = 0; i < 4; ++i)
#pragma unroll
            for (int j = 0; j < 2; ++j)
                acc[i][j] = __builtin_amdgcn_mfma_f32_16x16x32_bf16(af[i], bfr[j], acc[i][j], 0, 0, 0);
    }

    // xs staging: lane l of wave stages row wave*32+i*8+(l>>3), global chunk
    // (l&7)^(l>>3) -> LDS slot l (so LDS position p of row r holds chunk p^(r&7))
    const int xrow   = wave * 32 + (lane >> 3);
    const int xchunk = (lane & 7) ^ (lane >> 3);
    const uint16_t* xsrc = xb + (size_t)(m0 + xrow) * IN_F + xchunk * 8;

    for (int kt = 0; kt < NK; ++kt) {
        __syncthreads();   // A: all waves done reading previous LDS tiles

        // stage A tile via async global->LDS (16B/lane)
#pragma unroll
        for (int i = 0; i < 4; ++i) {
            __builtin_amdgcn_global_load_lds(
                (const __attribute__((address_space(1))) uint32_t*)(xsrc + kt * BK + (size_t)i * 8 * IN_F),
                (__attribute__((address_space(3))) uint32_t*)(xs + (wave * 32 + i * 8) * BK),
                16, 0, 0);
        }
        // stage W tile from prefetched registers: dequant -> bf16 ds_write
#pragma unroll
        for (int j = 0; j < 4; ++j) {
            const float s = sc[j];
            const float c = -128.f * s;
            const float f0 = fmaf((float)qv[j].x, s, c);
            const float f1 = fmaf((float)qv[j].y, s, c);
            const float f2 = fmaf((float)qv[j].z, s, c);
            const float f3 = fmaf((float)qv[j].w, s, c);
            uint2 p;
            p.x = pack_bf16(f0, f1);
            p.y = pack_bf16(f2, f3);
            *(uint2*)(wt + (qrow + 16 * j) * WP + qcol4) = p;
        }
        __syncthreads();   // B: tiles visible (drains xs lds-loads + ds_writes)

        // prefetch q for kt+1 — issued before MFMA so HBM latency overlaps it
        {
            const int ktn = (kt + 1) & (NK - 1);
#pragma unroll
            for (int j = 0; j < 4; ++j) {
                const int row = qrow + 16 * j;
                qv[j] = *(const int4*)(qbase + (size_t)row * IN_F + ktn * BK);
                sc[j] = scales[(size_t)(n0 + row) * (IN_F / 32) + ktn * 2 + qhi];
            }
        }

        // MFMA over the 64-wide K tile
#pragma unroll
        for (int kk = 0; kk < BK; kk += 32) {
            bf16x8 af[4], bfr[2];
#pragma unroll
            for (int i = 0; i < 4; ++i) {
                const int R = wm * 64 + i * 16 + fr;
                const int p = (((kk >> 3) + quad) ^ (fr & 7)) * 8;
                af[i] = *(const bf16x8*)(xs + R * BK + p);
            }
#pragma unroll
            for (int j = 0; j < 2; ++j)
                bfr[j] = *(const bf16x8*)(wt + (wn * 32 + j * 16 + fr) * WP + kk + fk);
#pragma unroll
            for (int i = 0; i < 4; ++i)
#pragma unroll
                for (int j = 0; j < 2; ++j)
                    acc[i][j] = __builtin_amdgcn_mfma_f32_16x16x32_bf16(af[i], bfr[j], acc[i][j], 0, 0, 0);
        }
    }

    // epilogue: + bias, store fp32 (C/D map: col=lane&15, row=quad*4+reg)
#pragma unroll
    for (int j = 0; j < 2; ++j) {
        const int col = n0 + wn * 32 + j * 16 + fr;
        const float bv = bias[col];
#pragma unroll
        for (int i = 0; i < 4; ++i) {
            const int rbase = m0 + wm * 64 + i * 16 + quad * 4;
#pragma unroll
            for (int r = 0; r < 4; ++r)
                out[(size_t)(rbase + r) * OUT_F + col] = acc[i][j][r] + bv;
        }
    }
}

extern "C" void kernel_launch(void* const* d_in, const int* in_sizes, int n_in,
                              void* d_out, int out_size, void* d_ws, size_t ws_size,
                              hipStream_t stream) {
    const float* x      = (const float*)d_in[0];
    const int*   q      = (const int*)d_in[1];
    const float* scales = (const float*)d_in[2];
    const float* lora_A = (const float*)d_in[3];
    const float* lora_B = (const float*)d_in[4];
    const float* bias   = (const float*)d_in[5];
    float* out = (float*)d_out;

    // ws layout: [0,16MB) xb bf16[1024][8192]; then t fp32[1024][16]
    uint16_t* xb = (uint16_t*)d_ws;
    float*    t  = (float*)((char*)d_ws + (size_t)M_TOT * IN_F * sizeof(uint16_t));

    convert_kernel<<<M_TOT, 256, 0, stream>>>(x, (uint2*)xb, t);   // also zeroes t
    lora_t_kernel<<<256, 256, 0, stream>>>(x, lora_A, t);
    gemm_kernel<<<(M_TOT / BM) * (OUT_F / BN), 256, 0, stream>>>(
        xb, q, scales, t, lora_B, bias, out);
}

// Round 3
// 606.578 us; speedup vs baseline: 1.0836x; 1.0298x over previous
//
#include <hip/hip_runtime.h>
#include <hip/hip_bf16.h>
#include <stdint.h>

#define OUT_F 8192
#define IN_F  8192
#define RANK  16
#define M_TOT 1024   // B*S
#define BM 128
#define BN 128
#define BK 64
#define NK (IN_F / BK)   // 128
#define SCB (IN_F / 32)  // 256 scale blocks per weight row

typedef __bf16 bf16x8 __attribute__((ext_vector_type(8)));
typedef float  f32x4  __attribute__((ext_vector_type(4)));

// round-half-up f32->bf16 pack of two floats into one uint32 (lo in low half)
static __device__ __forceinline__ uint32_t pack_bf16(float lo, float hi) {
    uint32_t a = __builtin_bit_cast(uint32_t, lo);
    uint32_t b = __builtin_bit_cast(uint32_t, hi);
    return ((a + 0x8000u) >> 16) | ((b + 0x8000u) & 0xffff0000u);
}

// ---------------------------------------------------------------------------
// Kernel 1: streaming fp32 -> bf16 convert of x into ws; blocks 0..63 also
// zero t (stream order guarantees t is zeroed before lora_t_kernel runs).
// ---------------------------------------------------------------------------
__global__ __launch_bounds__(256) void convert_kernel(
    const float* __restrict__ x, uint2* __restrict__ xb2, float* __restrict__ t)
{
    const int tid = threadIdx.x, b = blockIdx.x;
    if (b < 64) t[b * 256 + tid] = 0.f;
    const float4* x4 = (const float4*)x;
    const int base = b * 256 + tid;
#pragma unroll
    for (int j = 0; j < 8; ++j) {
        const int i = base + j * 262144;       // 2M float4 total
        const float4 v = x4[i];
        uint2 p;
        p.x = pack_bf16(v.x, v.y);
        p.y = pack_bf16(v.z, v.w);
        xb2[i] = p;
    }
}

// ---------------------------------------------------------------------------
// Kernel 2: t = x @ lora_A^T via MFMA split-K + atomicAdd.
// ---------------------------------------------------------------------------
__global__ __launch_bounds__(256) void lora_t_kernel(
    const float* __restrict__ x, const float* __restrict__ lora_A,
    float* __restrict__ t)
{
    const int b = blockIdx.x;
    const int mt = b >> 4, ks = b & 15;
    const int tid = threadIdx.x, wave = tid >> 6, lane = tid & 63;
    const int fr = lane & 15, quad = lane >> 4;
    const int m = mt * 64 + wave * 16 + fr;
    const int k0 = ks * 512 + quad * 8;

    f32x4 acc = {0.f, 0.f, 0.f, 0.f};
    const float* xr = x + (size_t)m * IN_F + k0;
    const float* ar = lora_A + (size_t)fr * IN_F + k0;

#pragma unroll 4
    for (int s = 0; s < 16; ++s) {
        const float4 x0 = *(const float4*)(xr + s * 32);
        const float4 x1 = *(const float4*)(xr + s * 32 + 4);
        const float4 a0 = *(const float4*)(ar + s * 32);
        const float4 a1 = *(const float4*)(ar + s * 32 + 4);
        bf16x8 af, bfr;
        uint32_t* ap = (uint32_t*)&af;
        uint32_t* bp = (uint32_t*)&bfr;
        ap[0] = pack_bf16(x0.x, x0.y); ap[1] = pack_bf16(x0.z, x0.w);
        ap[2] = pack_bf16(x1.x, x1.y); ap[3] = pack_bf16(x1.z, x1.w);
        bp[0] = pack_bf16(a0.x, a0.y); bp[1] = pack_bf16(a0.z, a0.w);
        bp[2] = pack_bf16(a1.x, a1.y); bp[3] = pack_bf16(a1.z, a1.w);
        acc = __builtin_amdgcn_mfma_f32_16x16x32_bf16(af, bfr, acc, 0, 0, 0);
    }
    const int mout = mt * 64 + wave * 16 + quad * 4;
#pragma unroll
    for (int r = 0; r < 4; ++r)
        atomicAdd(&t[(size_t)(mout + r) * RANK + fr], acc[r]);
}

// ---------------------------------------------------------------------------
// Kernel 3: fused dequant GEMM. 128x128 tile / block (grid 512, 2 blocks/CU),
// BK=64, 4 waves x 64x64 subtile, 4x4 mfma_f32_16x16x32_bf16.
// Both LDS tiles double-buffered + XOR-swizzled (64 KB total), ONE barrier
// per kt: every vmem op (xs DMA, q int4 prefetch) is issued a full kt before
// the barrier that drains it, so the compiler's vmcnt(0)-before-s_barrier
// costs ~nothing. q register pipeline is 2-deep (ping-pong qv[2]).
// ---------------------------------------------------------------------------

// One pipeline step: prefetch q for KT+2 into qv[P^1], DMA xs[NXT] for KT+1,
// dequant qv[P] (KT+1 data) into wt[NXT], MFMA from buffers [CUR], barrier.
#define GEMM_STEP(KT, P, CUR, NXT)                                             \
    {                                                                          \
        const int ktn = ((KT) + 2) & (NK - 1);                                 \
        _Pragma("unroll")                                                      \
        for (int j = 0; j < 8; ++j) {                                          \
            const int row = qrow + 16 * j;                                     \
            qv[(P) ^ 1][j] = *(const int4*)(qbase + (size_t)row * IN_F + ktn * BK); \
            sc[(P) ^ 1][j] = scales[(size_t)(n0 + row) * SCB + ktn * 2 + qhi]; \
        }                                                                      \
        const int kta = ((KT) + 1) & (NK - 1);                                 \
        _Pragma("unroll")                                                      \
        for (int i = 0; i < 4; ++i) {                                          \
            __builtin_amdgcn_global_load_lds(                                  \
                (const __attribute__((address_space(1))) uint32_t*)(xsrc + (size_t)kta * BK + (size_t)i * 8 * IN_F), \
                (__attribute__((address_space(3))) uint32_t*)(&xs[NXT][(wave * 32 + i * 8) * BK]), \
                16, 0, 0);                                                     \
        }                                                                      \
        _Pragma("unroll")                                                      \
        for (int j = 0; j < 8; ++j) {                                          \
            const float s = sc[P][j];                                          \
            const float c = -128.f * s;                                        \
            const int4 qq = qv[P][j];                                          \
            uint2 pk;                                                          \
            pk.x = pack_bf16(fmaf((float)qq.x, s, c), fmaf((float)qq.y, s, c)); \
            pk.y = pack_bf16(fmaf((float)qq.z, s, c), fmaf((float)qq.w, s, c)); \
            *(uint2*)(&wt[NXT][(qrow + 16 * j) * BK + wpos]) = pk;             \
        }                                                                      \
        _Pragma("unroll")                                                      \
        for (int kk = 0; kk < BK; kk += 32) {                                  \
            bf16x8 af[4], bfr[4];                                              \
            const int pp = (((kk >> 3) + quad) ^ (fr & 7)) * 8;                \
            _Pragma("unroll")                                                  \
            for (int i = 0; i < 4; ++i)                                        \
                af[i] = *(const bf16x8*)(&xs[CUR][(wm * 64 + i * 16 + fr) * BK + pp]); \
            _Pragma("unroll")                                                  \
            for (int j = 0; j < 4; ++j)                                        \
                bfr[j] = *(const bf16x8*)(&wt[CUR][(wn * 64 + j * 16 + fr) * BK + pp]); \
            _Pragma("unroll")                                                  \
            for (int i = 0; i < 4; ++i)                                        \
                _Pragma("unroll")                                              \
                for (int j = 0; j < 4; ++j)                                    \
                    acc[i][j] = __builtin_amdgcn_mfma_f32_16x16x32_bf16(af[i], bfr[j], acc[i][j], 0, 0, 0); \
        }                                                                      \
        __syncthreads();                                                       \
    }

__global__ __launch_bounds__(256, 2) void gemm_kernel(
    const uint16_t* __restrict__ xb,    // bf16 x  [1024][8192] (in ws)
    const int*      __restrict__ q,     // int32   [8192][8192]
    const float*    __restrict__ scales,// fp32    [8192][256]
    const float*    __restrict__ t,     // fp32    [1024][16]   (in ws)
    const float*    __restrict__ loraB, // fp32    [8192][16]
    const float*    __restrict__ bias,  // fp32    [8192]
    float*          __restrict__ out)   // fp32    [1024][8192]
{
    __shared__ __align__(16) uint16_t xs[2][BM * BK];   // 2 x 16 KB, swizzled A tiles
    __shared__ __align__(16) uint16_t wt[2][BN * BK];   // 2 x 16 KB, swizzled W tiles

    const int bx    = blockIdx.x;
    const int mtile = bx >> 6;          // 0..7
    const int ntile = bx & 63;          // 0..63 (same-ntile blocks -> same XCD)
    const int m0 = mtile * BM;
    const int n0 = ntile * BN;

    const int tid  = threadIdx.x;
    const int wave = tid >> 6;
    const int lane = tid & 63;
    const int wm = wave & 1, wn = wave >> 1;   // 64x64 wave subtile
    const int fr = lane & 15;
    const int quad = lane >> 4;

    // q staging map over the 128x64 int tile: thread t -> row (t>>4)+16j, ints (t&15)*4..+3
    const int qrow  = tid >> 4;
    const int qcol4 = (tid & 15) * 4;
    const int qhi   = (tid >> 3) & 1;
    // swizzled wt write position (constant across j since 16j % 8 == 0)
    const int wpos = ((((tid >> 1) & 7) ^ (qrow & 7)) * 8) + (tid & 1) * 4;

    const int* qbase = q + (size_t)n0 * IN_F + qcol4;

    f32x4 acc[4][4];
    const f32x4 z = {0.f, 0.f, 0.f, 0.f};
#pragma unroll
    for (int i = 0; i < 4; ++i)
#pragma unroll
        for (int j = 0; j < 4; ++j) acc[i][j] = z;

    int4  qv[2][8];
    float sc[2][8];

    // ---- prefetch q for kt=0 (covered by the LoRA prologue)
#pragma unroll
    for (int j = 0; j < 8; ++j) {
        const int row = qrow + 16 * j;
        qv[0][j] = *(const int4*)(qbase + (size_t)row * IN_F);
        sc[0][j] = scales[(size_t)(n0 + row) * SCB + qhi];
    }

    // ---- LoRA as one K=32 MFMA step: A'=t[m][r], B'=2*loraB[o][r], zero-padded.
    // Both tiles stored in the swizzled layout (chunk c of row r at slot c^(r&7)).
    {
        if (tid < 128) {
            const int row = tid, s = row & 7;
            const float4* tp = (const float4*)(t + (size_t)(m0 + row) * RANK);
            const float4 v0 = tp[0], v1 = tp[1], v2 = tp[2], v3 = tp[3];
            uint32_t vals[8];
            vals[0] = pack_bf16(v0.x, v0.y); vals[1] = pack_bf16(v0.z, v0.w);
            vals[2] = pack_bf16(v1.x, v1.y); vals[3] = pack_bf16(v1.z, v1.w);
            vals[4] = pack_bf16(v2.x, v2.y); vals[5] = pack_bf16(v2.z, v2.w);
            vals[6] = pack_bf16(v3.x, v3.y); vals[7] = pack_bf16(v3.z, v3.w);
            uint32_t* dst = (uint32_t*)(&xs[0][row * BK]);
#pragma unroll
            for (int c = 0; c < 8; ++c) {
                const int p = (c ^ s) * 4;
                if (c < 2) {
                    dst[p + 0] = vals[c * 4 + 0]; dst[p + 1] = vals[c * 4 + 1];
                    dst[p + 2] = vals[c * 4 + 2]; dst[p + 3] = vals[c * 4 + 3];
                } else {
                    dst[p + 0] = 0; dst[p + 1] = 0; dst[p + 2] = 0; dst[p + 3] = 0;
                }
            }
        } else {
            const int row = tid - 128, s = row & 7;
            const float4* bp = (const float4*)(loraB + (size_t)(n0 + row) * RANK);
            const float4 v0 = bp[0], v1 = bp[1], v2 = bp[2], v3 = bp[3];
            uint32_t vals[8];
            vals[0] = pack_bf16(2.f * v0.x, 2.f * v0.y); vals[1] = pack_bf16(2.f * v0.z, 2.f * v0.w);
            vals[2] = pack_bf16(2.f * v1.x, 2.f * v1.y); vals[3] = pack_bf16(2.f * v1.z, 2.f * v1.w);
            vals[4] = pack_bf16(2.f * v2.x, 2.f * v2.y); vals[5] = pack_bf16(2.f * v2.z, 2.f * v2.w);
            vals[6] = pack_bf16(2.f * v3.x, 2.f * v3.y); vals[7] = pack_bf16(2.f * v3.z, 2.f * v3.w);
            uint32_t* dst = (uint32_t*)(&wt[0][row * BK]);
#pragma unroll
            for (int c = 0; c < 8; ++c) {
                const int p = (c ^ s) * 4;
                if (c < 2) {
                    dst[p + 0] = vals[c * 4 + 0]; dst[p + 1] = vals[c * 4 + 1];
                    dst[p + 2] = vals[c * 4 + 2]; dst[p + 3] = vals[c * 4 + 3];
                } else {
                    dst[p + 0] = 0; dst[p + 1] = 0; dst[p + 2] = 0; dst[p + 3] = 0;
                }
            }
        }
        __syncthreads();
        const int pp = (quad ^ (fr & 7)) * 8;    // chunk=quad; quads 2,3 read zeros
        bf16x8 af[4], bfr[4];
#pragma unroll
        for (int i = 0; i < 4; ++i)
            af[i] = *(const bf16x8*)(&xs[0][(wm * 64 + i * 16 + fr) * BK + pp]);
#pragma unroll
        for (int j = 0; j < 4; ++j)
            bfr[j] = *(const bf16x8*)(&wt[0][(wn * 64 + j * 16 + fr) * BK + pp]);
#pragma unroll
        for (int i = 0; i < 4; ++i)
#pragma unroll
            for (int j = 0; j < 4; ++j)
                acc[i][j] = __builtin_amdgcn_mfma_f32_16x16x32_bf16(af[i], bfr[j], acc[i][j], 0, 0, 0);
        __syncthreads();   // LoRA reads done before buffers are restaged
    }

    // xs staging map: lane l stages row wave*32+i*8+(l>>3), global chunk
    // (l&7)^(l>>3), landing at LDS slot l&7 (swizzle realized via global perm).
    const int xrow   = wave * 32 + (lane >> 3);
    const int xchunk = (lane & 7) ^ (lane >> 3);
    const uint16_t* xsrc = xb + (size_t)(m0 + xrow) * IN_F + xchunk * 8;

    // ---- pipeline prologue: stage kt=0 into buffer 0, prefetch q for kt=1
#pragma unroll
    for (int i = 0; i < 4; ++i) {
        __builtin_amdgcn_global_load_lds(
            (const __attribute__((address_space(1))) uint32_t*)(xsrc + (size_t)i * 8 * IN_F),
            (__attribute__((address_space(3))) uint32_t*)(&xs[0][(wave * 32 + i * 8) * BK]),
            16, 0, 0);
    }
#pragma unroll
    for (int j = 0; j < 8; ++j) {
        const float s = sc[0][j];
        const float c = -128.f * s;
        const int4 qq = qv[0][j];
        uint2 pk;
        pk.x = pack_bf16(fmaf((float)qq.x, s, c), fmaf((float)qq.y, s, c));
        pk.y = pack_bf16(fmaf((float)qq.z, s, c), fmaf((float)qq.w, s, c));
        *(uint2*)(&wt[0][(qrow + 16 * j) * BK + wpos]) = pk;
    }
#pragma unroll
    for (int j = 0; j < 8; ++j) {
        const int row = qrow + 16 * j;
        qv[0][j] = *(const int4*)(qbase + (size_t)row * IN_F + 1 * BK);
        sc[0][j] = scales[(size_t)(n0 + row) * SCB + 2 + qhi];
    }
    __syncthreads();

    // ---- main loop, unrolled by 2 for the qv ping-pong
    for (int kt = 0; kt < NK; kt += 2) {
        GEMM_STEP(kt,     0, 0, 1);
        GEMM_STEP(kt + 1, 1, 1, 0);
    }

    // epilogue: + bias, store fp32 (C/D map: col=lane&15, row=quad*4+reg)
#pragma unroll
    for (int j = 0; j < 4; ++j) {
        const int col = n0 + wn * 64 + j * 16 + fr;
        const float bv = bias[col];
#pragma unroll
        for (int i = 0; i < 4; ++i) {
            const int rbase = m0 + wm * 64 + i * 16 + quad * 4;
#pragma unroll
            for (int r = 0; r < 4; ++r)
                out[(size_t)(rbase + r) * OUT_F + col] = acc[i][j][r] + bv;
        }
    }
}

extern "C" void kernel_launch(void* const* d_in, const int* in_sizes, int n_in,
                              void* d_out, int out_size, void* d_ws, size_t ws_size,
                              hipStream_t stream) {
    const float* x      = (const float*)d_in[0];
    const int*   q      = (const int*)d_in[1];
    const float* scales = (const float*)d_in[2];
    const float* lora_A = (const float*)d_in[3];
    const float* lora_B = (const float*)d_in[4];
    const float* bias   = (const float*)d_in[5];
    float* out = (float*)d_out;

    // ws layout: [0,16MB) xb bf16[1024][8192]; then t fp32[1024][16]
    uint16_t* xb = (uint16_t*)d_ws;
    float*    t  = (float*)((char*)d_ws + (size_t)M_TOT * IN_F * sizeof(uint16_t));

    convert_kernel<<<M_TOT, 256, 0, stream>>>(x, (uint2*)xb, t);   // also zeroes t
    lora_t_kernel<<<256, 256, 0, stream>>>(x, lora_A, t);
    gemm_kernel<<<(M_TOT / BM) * (OUT_F / BN), 256, 0, stream>>>(
        xb, q, scales, t, lora_B, bias, out);
}